// Round 4
// baseline (1197.484 us; speedup 1.0000x reference)
//
#include <hip/hip_runtime.h>
#include <stdint.h>

typedef unsigned short u16;
typedef __bf16 bf16x8 __attribute__((ext_vector_type(8)));
typedef float f32x4 __attribute__((ext_vector_type(4)));
typedef unsigned short u16x8 __attribute__((ext_vector_type(8)));

#define NBLK 512
#define N_SAMP 128
#define OPAD   224
#define ROWS   (N_SAMP * OPAD)   // 28672

// ---------- helpers ----------
__device__ __forceinline__ u16 f2b(float f) {
  union { float f; uint32_t u; } v; v.f = f;
  uint32_t r = v.u + 0x7fffu + ((v.u >> 16) & 1u);
  return (u16)(r >> 16);
}
__device__ __forceinline__ float b2f(u16 b) {
  union { float f; uint32_t u; } v; v.u = ((uint32_t)b) << 16;
  return v.f;
}
__device__ __forceinline__ void g2l16(const void* g, void* l) {
  __builtin_amdgcn_global_load_lds(
      (const __attribute__((address_space(1))) void*)g,
      (__attribute__((address_space(3))) void*)l, 16, 0, 0);
}

// ---------- grid barrier (all NBLK blocks co-resident by launch_bounds) ----------
__global__ void init_bar(int* bar) { if (threadIdx.x < 16) bar[threadIdx.x] = 0; }

__device__ __forceinline__ void gbar(int* bar, int idx) {
  __threadfence();                 // release: drain + make this block's stores device-visible
  __syncthreads();
  if (threadIdx.x == 0) {
    atomicAdd(&bar[idx], 1);       // device-scope by default
    int t = 0;
    while (__hip_atomic_load(&bar[idx], __ATOMIC_ACQUIRE, __HIP_MEMORY_SCOPE_AGENT) < NBLK) {
      __builtin_amdgcn_s_sleep(8);
      if (++t > 3000000) break;    // ~1s escape hatch: wrong answer instead of hang
    }
  }
  __syncthreads();
  __threadfence();                 // acquire: invalidate caches so we read fresh data
}

// ---------- S0a: image -> imgT[n][256 sp (16x16 zero-bordered)][1024 cin] bf16 ----------
__device__ void prep_img_part(char* smem, int b, const float* __restrict__ image,
                              u16* __restrict__ imgT) {
  float (*t)[197] = (float(*)[197])smem;   // 50,432 B
  int tid = threadIdx.x;
  for (int uu = 0; uu < 4; ++uu) {
    int unit = b * 4 + uu;
    int n = unit >> 4, cin0 = (unit & 15) << 6;
    const float* src = image + ((size_t)n * 1024 + cin0) * 196;
    __syncthreads();
    for (int e = tid; e < 64 * 196; e += 256) {
      int c = e / 196, sp = e - c * 196;
      t[c][sp] = src[c * 196 + sp];
    }
    __syncthreads();
    int cg = tid & 7, sg = tid >> 3;       // 8 cin-groups x 32 sp-groups
    for (int it = 0; it < 8; ++it) {
      int spg = it * 32 + sg;
      int gy = spg >> 4, gx = spg & 15;
      bool valid = (gy >= 1 && gy <= 14 && gx >= 1 && gx <= 14);
      int spi = (gy - 1) * 14 + (gx - 1);
      u16x8 v;
#pragma unroll
      for (int j = 0; j < 8; ++j) v[j] = valid ? f2b(t[cg * 8 + j][spi]) : (u16)0;
      *(u16x8*)(imgT + (((size_t)(n * 256 + spg)) << 10) + cin0 + cg * 8) = v;
    }
  }
}

// ---------- S0b: conv_w [cf][cin][9] -> W2 [9][cf][cin] bf16 ----------
__device__ void prep_w2(char* smem, int cf, const float* __restrict__ conv_w,
                        u16* __restrict__ W2) {
  float* wb = (float*)smem;                // 9216 floats = 36,864 B
  int tid = threadIdx.x;
  __syncthreads();
  for (int e = tid; e < 9216; e += 256) wb[e] = conv_w[(size_t)cf * 9216 + e];
  __syncthreads();
  int cin = tid * 4;
#pragma unroll
  for (int s = 0; s < 9; ++s) {
    ushort4 v;
    v.x = f2b(wb[(cin + 0) * 9 + s]);
    v.y = f2b(wb[(cin + 1) * 9 + s]);
    v.z = f2b(wb[(cin + 2) * 9 + s]);
    v.w = f2b(wb[(cin + 3) * 9 + s]);
    *(ushort4*)(W2 + (size_t)s * 131072 + cf * 1024 + cin) = v;
  }
}

// ---------- S0c: qeb cols 128..287 for valid rows of one n ----------
__device__ void prep_qe(char* smem, int n, const float* __restrict__ code,
                        u16* __restrict__ qeb) {
  u16* tmpl = (u16*)smem;
  int tid = threadIdx.x;
  __syncthreads();
  if (tid < 176) {
    int c = 128 + tid;
    u16 v = 0;
    if (c >= 130 && c < 258) v = f2b(code[n * 128 + c - 130]);
    tmpl[tid] = v;
  }
  __syncthreads();
  for (int it = 0; it < 16; ++it) {
    int ch = it * 256 + tid;
    if (ch < 3920) {                       // 196 rows x 20 chunks of 8
      int o = ch / 20, j = ch - o * 20;
      u16x8 v = *(const u16x8*)&tmpl[j * 8];
      if (j == 0) {
        int y = o / 14, x = o - y * 14;
        v[0] = f2b(-1.f + 2.f * y / 13.f);
        v[1] = f2b(-1.f + 2.f * x / 13.f);
      }
      *(u16x8*)(qeb + (size_t)(n * 224 + o) * 288 + 128 + j * 8) = v;
    }
  }
}

// ---------- S1: conv implicit GEMM (R2 structure), split-K 2 ----------
__device__ void conv_core(char* smem, int b, const u16* __restrict__ imgT,
                          const u16* __restrict__ W2, float* __restrict__ convAcc) {
  u16* lA = (u16*)smem;                    // 112*64*2 = 14,336 B
  u16* lB = (u16*)(smem + 14336);          // 128*64*2 = 16,384 B
  int tid = threadIdx.x, lane = tid & 63, w = tid >> 6;
  int xcd = b & 7, grp = b >> 3;           // same-n blocks on same XCD
  int n = ((grp >> 2) << 3) | xcd;
  int r4 = grp & 3;
  int oh = r4 >> 1, ks = r4 & 1;
  int oBase = oh * 112;
  size_t nBase = (size_t)n << 8;
  int rowIn = lane >> 3;
  int cA = ((lane & 7) ^ rowIn) << 3;      // XOR-swizzled chunk (elems)

  int yxA[4];
#pragma unroll
  for (int ii = 0; ii < 4; ++ii) {
    int t2 = w + ii * 4;
    int o = oBase + t2 * 8 + rowIn;
    bool valid = o < 196;
    int y = o / 14, x = o - y * 14;
    yxA[ii] = valid ? (y * 16 + x) : 0;    // invalid rows: garbage, discarded in epilogue
  }

  f32x4 acc[7][2];
#pragma unroll
  for (int mt = 0; mt < 7; ++mt)
#pragma unroll
    for (int j = 0; j < 2; ++j) acc[mt][j] = (f32x4){0.f, 0.f, 0.f, 0.f};

  int l = lane & 15, q = lane >> 4;
  int kbase = ks << 9;                     // split K by cin half
  for (int u = 0; u < 72; ++u) {
    int s = u >> 3;
    int k0 = kbase + ((u & 7) << 6);
    int s3 = s / 3;
    int off = s3 * 16 + (s - s3 * 3);      // dy*16+dx
    const u16* Ws = W2 + ((size_t)(s * 128) << 10);
    __syncthreads();
    g2l16(imgT + ((nBase + (size_t)(yxA[0] + off)) << 10) + k0 + cA, &lA[(w) * 512]);
    g2l16(imgT + ((nBase + (size_t)(yxA[1] + off)) << 10) + k0 + cA, &lA[(w + 4) * 512]);
    g2l16(imgT + ((nBase + (size_t)(yxA[2] + off)) << 10) + k0 + cA, &lA[(w + 8) * 512]);
    if (w < 2)
      g2l16(imgT + ((nBase + (size_t)(yxA[3] + off)) << 10) + k0 + cA, &lA[(w + 12) * 512]);
#pragma unroll
    for (int ii = 0; ii < 4; ++ii) {
      int t2 = w + ii * 4;
      g2l16(Ws + ((size_t)(t2 * 8 + rowIn) << 10) + k0 + cA, &lB[t2 * 512]);
    }
    __syncthreads();
#pragma unroll
    for (int kk = 0; kk < 2; ++kk) {
      int co = ((((kk << 2) | q) ^ (l & 7)) << 3);
      bf16x8 af[7];
#pragma unroll
      for (int mt = 0; mt < 7; ++mt)
        af[mt] = *(const bf16x8*)&lA[(mt * 16 + l) * 64 + co];
#pragma unroll
      for (int jj = 0; jj < 2; ++jj) {
        bf16x8 bb = *(const bf16x8*)&lB[(w * 32 + jj * 16 + l) * 64 + co];
#pragma unroll
        for (int mt = 0; mt < 7; ++mt)
          acc[mt][jj] = __builtin_amdgcn_mfma_f32_16x16x32_bf16(af[mt], bb, acc[mt][jj], 0, 0, 0);
      }
    }
  }
#pragma unroll
  for (int mt = 0; mt < 7; ++mt) {
    int o = oBase + mt * 16 + q * 4;
#pragma unroll
    for (int r4b = 0; r4b < 4; ++r4b) {
      if (o + r4b < 196) {
        float* dst = convAcc + (size_t)(n * 224 + o + r4b) * 128 + w * 32 + l;
        atomicAdd(dst, acc[mt][0][r4b]);
        atomicAdd(dst + 16, acc[mt][1][r4b]);
      }
    }
  }
}

// ---------- S3/S5/S6 GEMM core: C[112rows, 128cols] tiles, A[.,KP]*Bt[.,KP]^T ----------
template <int MODE>
__device__ void gemm_core(char* smem, int bx, int by,
                          const u16* __restrict__ A, const u16* __restrict__ Bt,
                          int KP, int KC,
                          const float* __restrict__ bias, const float* __restrict__ vec,
                          float* __restrict__ outF, u16* __restrict__ outB) {
  u16* lA = (u16*)smem;                    // 112*32*2 = 7168
  u16* lB = (u16*)(smem + 7168);           // 128*32*2 = 8192
  int tid = threadIdx.x, lane = tid & 63, w = tid >> 6;
  int r0 = bx * 112;
  int cBase = by * 128;
  int kb = (((lane & 3) ^ ((lane >> 3) & 3)) << 3);   // XOR-swizzled source chunk
  const u16* gA0 = A + (size_t)(r0 + w * 16 + (lane >> 2)) * KP + kb;
  const u16* gA1 = A + (size_t)(r0 + (w + 4) * 16 + (lane >> 2)) * KP + kb;
  bool has1 = (w < 3);
  const u16* gB0 = Bt + (size_t)(cBase + w * 16 + (lane >> 2)) * KP + kb;
  const u16* gB1 = Bt + (size_t)(cBase + (w + 4) * 16 + (lane >> 2)) * KP + kb;

  f32x4 acc[7][2];
#pragma unroll
  for (int mt = 0; mt < 7; ++mt)
#pragma unroll
    for (int j = 0; j < 2; ++j) acc[mt][j] = (f32x4){0.f, 0.f, 0.f, 0.f};
  int colW = w * 32;
  int l = lane & 15, q = lane >> 4;
  int co = ((q ^ ((l >> 1) & 3)) << 3);

  for (int cb = 0; cb < KC; ++cb) {
    __syncthreads();
    g2l16(gA0 + cb * 32, &lA[w * 512]);
    if (has1) g2l16(gA1 + cb * 32, &lA[(w + 4) * 512]);
    g2l16(gB0 + cb * 32, &lB[w * 512]);
    g2l16(gB1 + cb * 32, &lB[(w + 4) * 512]);
    __syncthreads();
    bf16x8 af[7];
#pragma unroll
    for (int mt = 0; mt < 7; ++mt)
      af[mt] = *(const bf16x8*)&lA[(mt * 16 + l) * 32 + co];
#pragma unroll
    for (int j = 0; j < 2; ++j) {
      bf16x8 bfr = *(const bf16x8*)&lB[(colW + j * 16 + l) * 32 + co];
#pragma unroll
      for (int mt = 0; mt < 7; ++mt)
        acc[mt][j] = __builtin_amdgcn_mfma_f32_16x16x32_bf16(af[mt], bfr, acc[mt][j], 0, 0, 0);
    }
  }

  if (MODE == 0) {                         // h_psi: relu(.+b0)*w1, row-reduce -> att atomics
    float attp[7][4];
#pragma unroll
    for (int mt = 0; mt < 7; ++mt)
#pragma unroll
      for (int r = 0; r < 4; ++r) attp[mt][r] = 0.f;
#pragma unroll
    for (int j = 0; j < 2; ++j) {
      int col = cBase + colW + j * 16 + l;
      float b0 = bias[col], w1 = vec[col];
#pragma unroll
      for (int mt = 0; mt < 7; ++mt)
#pragma unroll
        for (int r = 0; r < 4; ++r) {
          float v = fmaxf(acc[mt][j][r] + b0, 0.f);
          attp[mt][r] += v * w1;
        }
    }
#pragma unroll
    for (int mt = 0; mt < 7; ++mt)
#pragma unroll
      for (int r = 0; r < 4; ++r) {
        float p = attp[mt][r];
        p += __shfl_xor(p, 1, 64);
        p += __shfl_xor(p, 2, 64);
        p += __shfl_xor(p, 4, 64);
        p += __shfl_xor(p, 8, 64);
        if (l == 0) atomicAdd(&outF[r0 + mt * 16 + q * 4 + r], p);
      }
  } else if (MODE == 1) {                  // g_theta L1: relu(.+bias2[n]) -> g1 bf16
    int n = bx >> 1;
#pragma unroll
    for (int mt = 0; mt < 7; ++mt)
#pragma unroll
      for (int j = 0; j < 2; ++j) {
        int col = cBase + colW + j * 16 + l;
        float bb = bias[n * 256 + col];
#pragma unroll
        for (int r = 0; r < 4; ++r) {
          int row = r0 + mt * 16 + q * 4 + r;
          outB[(size_t)row * 256 + col] = f2b(fmaxf(acc[mt][j][r] + bb, 0.f));
        }
      }
  } else {                                 // g_theta L2: relu + masked row-sum -> relations
    int n = bx >> 1;
    int ob = (bx & 1) * 112;
#pragma unroll
    for (int j = 0; j < 2; ++j) {
      int col = cBase + colW + j * 16 + l;
      float bb = bias[col];
      float sum = 0.f;
#pragma unroll
      for (int mt = 0; mt < 7; ++mt)
#pragma unroll
        for (int r = 0; r < 4; ++r) {
          int o = ob + mt * 16 + q * 4 + r;
          if (o < 196) sum += fmaxf(acc[mt][j][r] + bb, 0.f);
        }
      sum += __shfl_xor(sum, 16, 64);
      sum += __shfl_xor(sum, 32, 64);
      if (q == 0) atomicAdd(&outF[n * 256 + col], sum);
    }
  }
}

// ---------- S4: softmax select -> per-n bias2 ----------
__device__ void sel_part(char* smem, int n, const float* __restrict__ att,
                         const u16* __restrict__ qeb, const float* __restrict__ gt_w0,
                         const float* __restrict__ gt_b0, float* __restrict__ bias2) {
  float* sm = (float*)smem;                // 196
  float* red = sm + 200;                   // 8
  float* part = red + 8;                   // 4*130
  float* sel = part + 520;                 // 130
  int t = threadIdx.x, w = t >> 6, lane = t & 63;
  float a = (t < 196) ? att[n * 224 + t] : -1e30f;
  float m = a;
  for (int mask = 1; mask < 64; mask <<= 1) m = fmaxf(m, __shfl_xor(m, mask, 64));
  if (lane == 0) red[w] = m;
  __syncthreads();
  float M = fmaxf(fmaxf(red[0], red[1]), fmaxf(red[2], red[3]));
  float e = (t < 196) ? expf(a - M) : 0.f;
  float sAcc = e;
  for (int mask = 1; mask < 64; mask <<= 1) sAcc += __shfl_xor(sAcc, mask, 64);
  if (lane == 0) red[4 + w] = sAcc;
  __syncthreads();
  float S = red[4] + red[5] + red[6] + red[7];
  if (t < 196) sm[t] = e / S;
  __syncthreads();
  // selected[c] = sum_o sm[o] * qeb[o][c], c in [0,130): wave partials, coalesced reads
  float p1 = 0.f, p2 = 0.f, p3 = 0.f;
  for (int o = w; o < 196; o += 4) {
    float s = sm[o];
    const u16* row = qeb + (size_t)(n * 224 + o) * 288;
    p1 += s * b2f(row[lane]);
    p2 += s * b2f(row[64 + lane]);
    if (lane < 2) p3 += s * b2f(row[128 + lane]);
  }
  part[w * 130 + lane] = p1;
  part[w * 130 + 64 + lane] = p2;
  if (lane < 2) part[w * 130 + 128 + lane] = p3;
  __syncthreads();
  if (t < 130) sel[t] = part[t] + part[130 + t] + part[260 + t] + part[390 + t];
  __syncthreads();
  float acc2 = gt_b0[t];
  for (int d = 0; d < 130; ++d) acc2 += sel[d] * gt_w0[(258 + d) * 256 + t];
  bias2[n * 256 + t] = acc2;
}

// ---------- S7: f_phi ----------
__device__ void fphi_part(char* smem, int n, const float* __restrict__ relations,
                          const float* __restrict__ fp_w0, const float* __restrict__ fp_b0,
                          const float* __restrict__ fp_w1, const float* __restrict__ fp_b1,
                          float* __restrict__ out) {
  float* rel = (float*)smem;
  float* f = rel + 256;
  int t = threadIdx.x;
  rel[t] = relations[n * 256 + t];
  __syncthreads();
  float acc = fp_b0[t];
  for (int k = 0; k < 256; ++k) acc += rel[k] * fp_w0[k * 256 + t];
  f[t] = fmaxf(acc, 0.f);
  __syncthreads();
  if (t < 32) {
    float o = fp_b1[0];
    for (int k = 0; k < 256; ++k) o += f[k] * fp_w1[k * 32 + t];
    out[n * 32 + t] = o;
  }
}

// ---------- the megakernel ----------
__global__ __launch_bounds__(256, 2) void mega(
    const float* image, const float* code, const float* conv_w, const float* conv_b,
    const float* hp_w0, const float* hp_b0, const float* hp_w1,
    const float* gt_w0, const float* gt_b0, const float* gt_w1, const float* gt_b1,
    const float* fp_w0, const float* fp_b0, const float* fp_w1, const float* fp_b1,
    u16* imgT, u16* W2, u16* qeb, u16* hp_w0t, u16* gt_w0t, u16* gt_w1t,
    float* att, float* bias2, float* convAcc, float* relations, float* out, int* bar) {
  __shared__ __align__(16) char smem[50432];
  int b = blockIdx.x, tid = threadIdx.x;

  // ---- S0: prep (imgT for all; extra task by block range) ----
  prep_img_part(smem, b, image, imgT);
  if (b < 128) {
    prep_w2(smem, b, conv_w, W2);
  } else if (b < 256) {
    prep_qe(smem, b - 128, code, qeb);
  } else if (b < 384) {
    int z = b - 256;
    f32x4 zz = {0.f, 0.f, 0.f, 0.f};
    float* za = convAcc + (size_t)z * 28672;
#pragma unroll 4
    for (int i2 = 0; i2 < 28; ++i2) *(f32x4*)(za + (size_t)(i2 * 256 + tid) * 4) = zz;
    if (tid < 56) *(f32x4*)(att + (size_t)(z * 56 + tid) * 4) = zz;
    if (tid < 64) *(f32x4*)(relations + (size_t)(z * 64 + tid) * 4) = zz;
  } else {
    int z = b - 384;
    for (int e = tid; e < 576; e += 256) {
      int idx = z * 576 + e;
      int nn = idx / 288, kk = idx - nn * 288;
      hp_w0t[idx] = (kk < 258) ? f2b(hp_w0[kk * 256 + nn]) : (u16)0;
    }
    for (int e = tid; e < 576; e += 256) {
      int idx = z * 576 + e;
      int nn = idx / 288, kk = idx - nn * 288;
      gt_w0t[idx] = (kk < 258) ? f2b(gt_w0[kk * 256 + nn]) : (u16)0;
    }
    for (int e = tid; e < 512; e += 256) {
      int idx = z * 512 + e;
      int nn = idx >> 8, kk = idx & 255;
      gt_w1t[idx] = f2b(gt_w1[kk * 256 + nn]);
    }
  }
  gbar(bar, 0);

  // ---- S1: conv ----
  conv_core(smem, b, imgT, W2, convAcc);
  gbar(bar, 1);

  // ---- S2: convAcc + bias -> qeb bf16 cols 0..127 ----
  for (int u2 = b * 256 + tid; u2 < 128 * 196 * 32; u2 += NBLK * 256) {
    int row196 = u2 >> 5;
    int c0 = (u2 & 31) << 2;
    int n = row196 / 196, o = row196 - n * 196;
    size_t row = (size_t)(n * 224 + o);
    float4 v = *(const float4*)(convAcc + (row << 7) + c0);
    float4 bb = *(const float4*)(conv_b + c0);
    ushort4 pk;
    pk.x = f2b(v.x + bb.x); pk.y = f2b(v.y + bb.y);
    pk.z = f2b(v.z + bb.z); pk.w = f2b(v.w + bb.w);
    *(ushort4*)(qeb + row * 288 + c0) = pk;
  }
  gbar(bar, 2);

  // ---- S3: h_psi -> att ----
  gemm_core<0>(smem, b & 255, b >> 8, qeb, hp_w0t, 288, 9, hp_b0, hp_w1, att, nullptr);
  gbar(bar, 3);

  // ---- S4: softmax select -> bias2 ----
  if (b < 128) sel_part(smem, b, att, qeb, gt_w0, gt_b0, bias2);
  gbar(bar, 4);

  // ---- S5: g_theta L1 -> g1 (aliases convAcc) ----
  gemm_core<1>(smem, b & 255, b >> 8, qeb, gt_w0t, 288, 9, bias2, nullptr, nullptr, (u16*)convAcc);
  gbar(bar, 5);

  // ---- S6: g_theta L2 -> relations ----
  gemm_core<2>(smem, b & 255, b >> 8, (const u16*)convAcc, gt_w1t, 256, 8, gt_b1, nullptr,
               relations, nullptr);
  gbar(bar, 6);

  // ---- S7: f_phi -> out ----
  if (b < 128) fphi_part(smem, b, relations, fp_w0, fp_b0, fp_w1, fp_b1, out);
}

extern "C" void kernel_launch(void* const* d_in, const int* in_sizes, int n_in,
                              void* d_out, int out_size, void* d_ws, size_t ws_size,
                              hipStream_t stream) {
  const float* image = (const float*)d_in[0];
  const float* code = (const float*)d_in[1];
  const float* conv_w = (const float*)d_in[2];
  const float* conv_b = (const float*)d_in[3];
  const float* hp_w0 = (const float*)d_in[4];
  const float* hp_b0 = (const float*)d_in[5];
  const float* hp_w1 = (const float*)d_in[6];
  /* hp_b1: softmax shift-invariant, dropped */
  const float* gt_w0 = (const float*)d_in[8];
  const float* gt_b0 = (const float*)d_in[9];
  const float* gt_w1 = (const float*)d_in[10];
  const float* gt_b1 = (const float*)d_in[11];
  const float* fp_w0 = (const float*)d_in[12];
  const float* fp_b0 = (const float*)d_in[13];
  const float* fp_w1 = (const float*)d_in[14];
  const float* fp_b1 = (const float*)d_in[15];
  float* out = (float*)d_out;

  char* p = (char*)d_ws;
  u16* imgT = (u16*)p;   p += (size_t)128 * 256 * 1024 * 2;   // 67.1 MB
  u16* W2 = (u16*)p;     p += (size_t)9 * 128 * 1024 * 2;     // 2.36 MB
  u16* qeb = (u16*)p;    p += (size_t)ROWS * 288 * 2;         // 16.5 MB
  u16* hp_w0t = (u16*)p; p += (size_t)256 * 288 * 2;
  u16* gt_w0t = (u16*)p; p += (size_t)256 * 288 * 2;
  u16* gt_w1t = (u16*)p; p += (size_t)256 * 256 * 2;
  float* att = (float*)p;   p += (size_t)ROWS * 4;
  float* bias2 = (float*)p; p += (size_t)128 * 256 * 4;
  float* convAcc = (float*)p; p += (size_t)ROWS * 128 * 4;    // 14.7 MB; reused as g1
  float* relations = (float*)p; p += (size_t)128 * 256 * 4;
  int* bar = (int*)p;    p += 64;

  init_bar<<<1, 64, 0, stream>>>(bar);
  mega<<<NBLK, 256, 0, stream>>>(image, code, conv_w, conv_b, hp_w0, hp_b0, hp_w1,
                                 gt_w0, gt_b0, gt_w1, gt_b1, fp_w0, fp_b0, fp_w1, fp_b1,
                                 imgT, W2, qeb, hp_w0t, gt_w0t, gt_w1t,
                                 att, bias2, convAcc, relations, out, bar);
}

// Round 6
// 1011.699 us; speedup vs baseline: 1.1836x; 1.1836x over previous
//
#include <hip/hip_runtime.h>
#include <stdint.h>

typedef unsigned short u16;
typedef __bf16 bf16x8 __attribute__((ext_vector_type(8)));
typedef float f32x4 __attribute__((ext_vector_type(4)));
typedef unsigned short u16x8 __attribute__((ext_vector_type(8)));

#define NBLK 512
#define N_SAMP 128
#define OPAD   224
#define ROWS   (N_SAMP * OPAD)   // 28672

// ---------- helpers ----------
__device__ __forceinline__ u16 f2b(float f) {
  union { float f; uint32_t u; } v; v.f = f;
  uint32_t r = v.u + 0x7fffu + ((v.u >> 16) & 1u);
  return (u16)(r >> 16);
}
__device__ __forceinline__ float b2f(u16 b) {
  union { float f; uint32_t u; } v; v.u = ((uint32_t)b) << 16;
  return v.f;
}
__device__ __forceinline__ void g2l16(const void* g, void* l) {
  __builtin_amdgcn_global_load_lds(
      (const __attribute__((address_space(1))) void*)g,
      (__attribute__((address_space(3))) void*)l, 16, 0, 0);
}

// ---------- grid barrier ----------
// R4 lesson: ACQUIRE-scope polling emits buffer_inv per poll -> L2 permanently
// cold -> 3% utilization. Fix: RELAXED system-scope poll (read-through, no
// invalidate); ONE acquire fence after the spin.
// R5 lesson: NBLK=768 @ launch_bounds(256,3) deadlocked (3x50.7KB LDS did not
// co-reside despite 160KB spec). NBLK=512 @ (256,2) is empirically co-resident.
__global__ void init_bar(int* bar) { if (threadIdx.x < 16) bar[threadIdx.x] = 0; }

__device__ __forceinline__ void gbar(int* bar, int idx) {
  __threadfence();                 // release: write back this block's stores
  __syncthreads();
  if (threadIdx.x == 0) {
    atomicAdd(&bar[idx], 1);       // device-scope RMW at coherent point
    int t = 0;
    while (__hip_atomic_load(&bar[idx], __ATOMIC_RELAXED,
                             __HIP_MEMORY_SCOPE_SYSTEM) < NBLK) {
      __builtin_amdgcn_s_sleep(8);
      if (++t > (1 << 20)) break;  // escape: wrong answer instead of hang
    }
  }
  __syncthreads();
  __threadfence();                 // acquire ONCE: invalidate stale L1/L2
}

// ---------- S0a: image -> imgT[n][256 sp (16x16 zero-bordered)][1024 cin] bf16 ----------
__device__ void prep_img_part(char* smem, int b, const float* __restrict__ image,
                              u16* __restrict__ imgT) {
  float (*t)[197] = (float(*)[197])smem;   // 50,432 B
  int tid = threadIdx.x;
  for (int uu = 0; uu < 4; ++uu) {
    int unit = b * 4 + uu;                 // 512*4 = 2048 units
    int n = unit >> 4, cin0 = (unit & 15) << 6;
    const float* src = image + ((size_t)n * 1024 + cin0) * 196;
    __syncthreads();
    for (int e = tid; e < 64 * 196; e += 256) {
      int c = e / 196, sp = e - c * 196;
      t[c][sp] = src[c * 196 + sp];
    }
    __syncthreads();
    int cg = tid & 7, sg = tid >> 3;       // 8 cin-groups x 32 sp-groups
    for (int it = 0; it < 8; ++it) {
      int spg = it * 32 + sg;
      int gy = spg >> 4, gx = spg & 15;
      bool valid = (gy >= 1 && gy <= 14 && gx >= 1 && gx <= 14);
      int spi = (gy - 1) * 14 + (gx - 1);
      u16x8 v;
#pragma unroll
      for (int j = 0; j < 8; ++j) v[j] = valid ? f2b(t[cg * 8 + j][spi]) : (u16)0;
      *(u16x8*)(imgT + (((size_t)(n * 256 + spg)) << 10) + cin0 + cg * 8) = v;
    }
  }
}

// ---------- S0b: conv_w [cf][cin][9] -> W2 [9][cf][cin] bf16 ----------
__device__ void prep_w2(char* smem, int cf, const float* __restrict__ conv_w,
                        u16* __restrict__ W2) {
  float* wb = (float*)smem;                // 36,864 B
  int tid = threadIdx.x;
  __syncthreads();
  for (int e = tid; e < 9216; e += 256) wb[e] = conv_w[(size_t)cf * 9216 + e];
  __syncthreads();
  int cin = tid * 4;
#pragma unroll
  for (int s = 0; s < 9; ++s) {
    ushort4 v;
    v.x = f2b(wb[(cin + 0) * 9 + s]);
    v.y = f2b(wb[(cin + 1) * 9 + s]);
    v.z = f2b(wb[(cin + 2) * 9 + s]);
    v.w = f2b(wb[(cin + 3) * 9 + s]);
    *(ushort4*)(W2 + (size_t)s * 131072 + cf * 1024 + cin) = v;
  }
}

// ---------- S0c: qeb cols 128..287 for valid rows of one n ----------
__device__ void prep_qe(char* smem, int n, const float* __restrict__ code,
                        u16* __restrict__ qeb) {
  u16* tmpl = (u16*)smem;
  int tid = threadIdx.x;
  __syncthreads();
  if (tid < 176) {
    int c = 128 + tid;
    u16 v = 0;
    if (c >= 130 && c < 258) v = f2b(code[n * 128 + c - 130]);
    tmpl[tid] = v;
  }
  __syncthreads();
  for (int it = 0; it < 16; ++it) {
    int ch = it * 256 + tid;
    if (ch < 3920) {                       // 196 rows x 20 chunks of 8
      int o = ch / 20, j = ch - o * 20;
      u16x8 v = *(const u16x8*)&tmpl[j * 8];
      if (j == 0) {
        int y = o / 14, x = o - y * 14;
        v[0] = f2b(-1.f + 2.f * y / 13.f);
        v[1] = f2b(-1.f + 2.f * x / 13.f);
      }
      *(u16x8*)(qeb + (size_t)(n * 224 + o) * 288 + 128 + j * 8) = v;
    }
  }
}

// ---------- S1: conv implicit GEMM (R2 structure), split-K 2 ----------
__device__ void conv_core(char* smem, int b, const u16* __restrict__ imgT,
                          const u16* __restrict__ W2, float* __restrict__ convAcc) {
  u16* lA = (u16*)smem;                    // 14,336 B
  u16* lB = (u16*)(smem + 14336);          // 16,384 B
  int tid = threadIdx.x, lane = tid & 63, w = tid >> 6;
  int xcd = b & 7, grp = b >> 3;           // same-n blocks on same XCD
  int n = ((grp >> 2) << 3) | xcd;
  int r4 = grp & 3;
  int oh = r4 >> 1, ks = r4 & 1;
  int oBase = oh * 112;
  size_t nBase = (size_t)n << 8;
  int rowIn = lane >> 3;
  int cA = ((lane & 7) ^ rowIn) << 3;      // XOR-swizzled chunk (elems)

  int yxA[4];
#pragma unroll
  for (int ii = 0; ii < 4; ++ii) {
    int t2 = w + ii * 4;
    int o = oBase + t2 * 8 + rowIn;
    bool valid = o < 196;
    int y = o / 14, x = o - y * 14;
    yxA[ii] = valid ? (y * 16 + x) : 0;    // invalid rows: garbage, discarded in epilogue
  }

  f32x4 acc[7][2];
#pragma unroll
  for (int mt = 0; mt < 7; ++mt)
#pragma unroll
    for (int j = 0; j < 2; ++j) acc[mt][j] = (f32x4){0.f, 0.f, 0.f, 0.f};

  int l = lane & 15, q = lane >> 4;
  int kbase = ks << 9;                     // split K by cin half
  for (int u = 0; u < 72; ++u) {
    int s = u >> 3;
    int k0 = kbase + ((u & 7) << 6);
    int s3 = s / 3;
    int off = s3 * 16 + (s - s3 * 3);      // dy*16+dx
    const u16* Ws = W2 + ((size_t)(s * 128) << 10);
    __syncthreads();
    g2l16(imgT + ((nBase + (size_t)(yxA[0] + off)) << 10) + k0 + cA, &lA[(w) * 512]);
    g2l16(imgT + ((nBase + (size_t)(yxA[1] + off)) << 10) + k0 + cA, &lA[(w + 4) * 512]);
    g2l16(imgT + ((nBase + (size_t)(yxA[2] + off)) << 10) + k0 + cA, &lA[(w + 8) * 512]);
    if (w < 2)
      g2l16(imgT + ((nBase + (size_t)(yxA[3] + off)) << 10) + k0 + cA, &lA[(w + 12) * 512]);
#pragma unroll
    for (int ii = 0; ii < 4; ++ii) {
      int t2 = w + ii * 4;
      g2l16(Ws + ((size_t)(t2 * 8 + rowIn) << 10) + k0 + cA, &lB[t2 * 512]);
    }
    __syncthreads();
#pragma unroll
    for (int kk = 0; kk < 2; ++kk) {
      int co = ((((kk << 2) | q) ^ (l & 7)) << 3);
      bf16x8 af[7];
#pragma unroll
      for (int mt = 0; mt < 7; ++mt)
        af[mt] = *(const bf16x8*)&lA[(mt * 16 + l) * 64 + co];
#pragma unroll
      for (int jj = 0; jj < 2; ++jj) {
        bf16x8 bb = *(const bf16x8*)&lB[(w * 32 + jj * 16 + l) * 64 + co];
#pragma unroll
        for (int mt = 0; mt < 7; ++mt)
          acc[mt][jj] = __builtin_amdgcn_mfma_f32_16x16x32_bf16(af[mt], bb, acc[mt][jj], 0, 0, 0);
      }
    }
  }
#pragma unroll
  for (int mt = 0; mt < 7; ++mt) {
    int o = oBase + mt * 16 + q * 4;
#pragma unroll
    for (int r4b = 0; r4b < 4; ++r4b) {
      if (o + r4b < 196) {
        float* dst = convAcc + (size_t)(n * 224 + o + r4b) * 128 + w * 32 + l;
        atomicAdd(dst, acc[mt][0][r4b]);
        atomicAdd(dst + 16, acc[mt][1][r4b]);
      }
    }
  }
}

// ---------- S3/S5/S6 GEMM core ----------
template <int MODE>
__device__ void gemm_core(char* smem, int bx, int by,
                          const u16* __restrict__ A, const u16* __restrict__ Bt,
                          int KP, int KC,
                          const float* __restrict__ bias, const float* __restrict__ vec,
                          float* __restrict__ outF, u16* __restrict__ outB) {
  u16* lA = (u16*)smem;                    // 7,168
  u16* lB = (u16*)(smem + 7168);           // 8,192
  int tid = threadIdx.x, lane = tid & 63, w = tid >> 6;
  int r0 = bx * 112;
  int cBase = by * 128;
  int kb = (((lane & 3) ^ ((lane >> 3) & 3)) << 3);
  const u16* gA0 = A + (size_t)(r0 + w * 16 + (lane >> 2)) * KP + kb;
  const u16* gA1 = A + (size_t)(r0 + (w + 4) * 16 + (lane >> 2)) * KP + kb;
  bool has1 = (w < 3);
  const u16* gB0 = Bt + (size_t)(cBase + w * 16 + (lane >> 2)) * KP + kb;
  const u16* gB1 = Bt + (size_t)(cBase + (w + 4) * 16 + (lane >> 2)) * KP + kb;

  f32x4 acc[7][2];
#pragma unroll
  for (int mt = 0; mt < 7; ++mt)
#pragma unroll
    for (int j = 0; j < 2; ++j) acc[mt][j] = (f32x4){0.f, 0.f, 0.f, 0.f};
  int colW = w * 32;
  int l = lane & 15, q = lane >> 4;
  int co = ((q ^ ((l >> 1) & 3)) << 3);

  for (int cb = 0; cb < KC; ++cb) {
    __syncthreads();
    g2l16(gA0 + cb * 32, &lA[w * 512]);
    if (has1) g2l16(gA1 + cb * 32, &lA[(w + 4) * 512]);
    g2l16(gB0 + cb * 32, &lB[w * 512]);
    g2l16(gB1 + cb * 32, &lB[(w + 4) * 512]);
    __syncthreads();
    bf16x8 af[7];
#pragma unroll
    for (int mt = 0; mt < 7; ++mt)
      af[mt] = *(const bf16x8*)&lA[(mt * 16 + l) * 32 + co];
#pragma unroll
    for (int j = 0; j < 2; ++j) {
      bf16x8 bfr = *(const bf16x8*)&lB[(colW + j * 16 + l) * 32 + co];
#pragma unroll
      for (int mt = 0; mt < 7; ++mt)
        acc[mt][j] = __builtin_amdgcn_mfma_f32_16x16x32_bf16(af[mt], bfr, acc[mt][j], 0, 0, 0);
    }
  }

  if (MODE == 0) {                         // h_psi -> att atomics
    float attp[7][4];
#pragma unroll
    for (int mt = 0; mt < 7; ++mt)
#pragma unroll
      for (int r = 0; r < 4; ++r) attp[mt][r] = 0.f;
#pragma unroll
    for (int j = 0; j < 2; ++j) {
      int col = cBase + colW + j * 16 + l;
      float b0 = bias[col], w1 = vec[col];
#pragma unroll
      for (int mt = 0; mt < 7; ++mt)
#pragma unroll
        for (int r = 0; r < 4; ++r) {
          float v = fmaxf(acc[mt][j][r] + b0, 0.f);
          attp[mt][r] += v * w1;
        }
    }
#pragma unroll
    for (int mt = 0; mt < 7; ++mt)
#pragma unroll
      for (int r = 0; r < 4; ++r) {
        float p = attp[mt][r];
        p += __shfl_xor(p, 1, 64);
        p += __shfl_xor(p, 2, 64);
        p += __shfl_xor(p, 4, 64);
        p += __shfl_xor(p, 8, 64);
        if (l == 0) atomicAdd(&outF[r0 + mt * 16 + q * 4 + r], p);
      }
  } else if (MODE == 1) {                  // g_theta L1 -> g1 bf16
    int n = bx >> 1;
#pragma unroll
    for (int mt = 0; mt < 7; ++mt)
#pragma unroll
      for (int j = 0; j < 2; ++j) {
        int col = cBase + colW + j * 16 + l;
        float bb = bias[n * 256 + col];
#pragma unroll
        for (int r = 0; r < 4; ++r) {
          int row = r0 + mt * 16 + q * 4 + r;
          outB[(size_t)row * 256 + col] = f2b(fmaxf(acc[mt][j][r] + bb, 0.f));
        }
      }
  } else {                                 // g_theta L2 -> relations atomics
    int n = bx >> 1;
    int ob = (bx & 1) * 112;
#pragma unroll
    for (int j = 0; j < 2; ++j) {
      int col = cBase + colW + j * 16 + l;
      float bb = bias[col];
      float sum = 0.f;
#pragma unroll
      for (int mt = 0; mt < 7; ++mt)
#pragma unroll
        for (int r = 0; r < 4; ++r) {
          int o = ob + mt * 16 + q * 4 + r;
          if (o < 196) sum += fmaxf(acc[mt][j][r] + bb, 0.f);
        }
      sum += __shfl_xor(sum, 16, 64);
      sum += __shfl_xor(sum, 32, 64);
      if (q == 0) atomicAdd(&outF[n * 256 + col], sum);
    }
  }
}

// ---------- S4: softmax select -> per-n bias2 ----------
__device__ void sel_part(char* smem, int n, const float* __restrict__ att,
                         const u16* __restrict__ qeb, const float* __restrict__ gt_w0,
                         const float* __restrict__ gt_b0, float* __restrict__ bias2) {
  float* sm = (float*)smem;                // 196 (pad 200)
  float* red = sm + 200;                   // 8
  float* part = red + 8;                   // 4*130
  float* sel = part + 520;                 // 130
  int t = threadIdx.x, w = t >> 6, lane = t & 63;
  float a = (t < 196) ? att[n * 224 + t] : -1e30f;
  float m = a;
  for (int mask = 1; mask < 64; mask <<= 1) m = fmaxf(m, __shfl_xor(m, mask, 64));
  if (lane == 0) red[w] = m;
  __syncthreads();
  float M = fmaxf(fmaxf(red[0], red[1]), fmaxf(red[2], red[3]));
  float e = (t < 196) ? expf(a - M) : 0.f;
  float sAcc = e;
  for (int mask = 1; mask < 64; mask <<= 1) sAcc += __shfl_xor(sAcc, mask, 64);
  if (lane == 0) red[4 + w] = sAcc;
  __syncthreads();
  float S = red[4] + red[5] + red[6] + red[7];
  if (t < 196) sm[t] = e / S;
  __syncthreads();
  float p1 = 0.f, p2 = 0.f, p3 = 0.f;
  for (int o = w; o < 196; o += 4) {
    float s = sm[o];
    const u16* row = qeb + (size_t)(n * 224 + o) * 288;
    p1 += s * b2f(row[lane]);
    p2 += s * b2f(row[64 + lane]);
    if (lane < 2) p3 += s * b2f(row[128 + lane]);
  }
  part[w * 130 + lane] = p1;
  part[w * 130 + 64 + lane] = p2;
  if (lane < 2) part[w * 130 + 128 + lane] = p3;
  __syncthreads();
  if (t < 130) sel[t] = part[t] + part[130 + t] + part[260 + t] + part[390 + t];
  __syncthreads();
  float acc2 = gt_b0[t];
  for (int d = 0; d < 130; ++d) acc2 += sel[d] * gt_w0[(258 + d) * 256 + t];
  bias2[n * 256 + t] = acc2;
}

// ---------- S7: f_phi ----------
__device__ void fphi_part(char* smem, int n, const float* __restrict__ relations,
                          const float* __restrict__ fp_w0, const float* __restrict__ fp_b0,
                          const float* __restrict__ fp_w1, const float* __restrict__ fp_b1,
                          float* __restrict__ out) {
  float* rel = (float*)smem;
  float* f = rel + 256;
  int t = threadIdx.x;
  rel[t] = relations[n * 256 + t];
  __syncthreads();
  float acc = fp_b0[t];
  for (int k = 0; k < 256; ++k) acc += rel[k] * fp_w0[k * 256 + t];
  f[t] = fmaxf(acc, 0.f);
  __syncthreads();
  if (t < 32) {
    float o = fp_b1[0];
    for (int k = 0; k < 256; ++k) o += f[k] * fp_w1[k * 32 + t];
    out[n * 32 + t] = o;
  }
}

// ---------- the megakernel ----------
__global__ __launch_bounds__(256, 2) void mega(
    const float* image, const float* code, const float* conv_w, const float* conv_b,
    const float* hp_w0, const float* hp_b0, const float* hp_w1,
    const float* gt_w0, const float* gt_b0, const float* gt_w1, const float* gt_b1,
    const float* fp_w0, const float* fp_b0, const float* fp_w1, const float* fp_b1,
    u16* imgT, u16* W2, u16* qeb, u16* hp_w0t, u16* gt_w0t, u16* gt_w1t,
    float* att, float* bias2, float* convAcc, float* relations, float* out, int* bar) {
  __shared__ __align__(16) char smem[50432];
  int b = blockIdx.x, tid = threadIdx.x;

  // ---- S0: prep (img transpose 4 units/block; extra task by block range) ----
  prep_img_part(smem, b, image, imgT);
  if (b < 128) {
    prep_w2(smem, b, conv_w, W2);
  } else if (b < 256) {
    prep_qe(smem, b - 128, code, qeb);
  } else if (b < 384) {
    int z = b - 256;
    f32x4 zz = {0.f, 0.f, 0.f, 0.f};
    float* za = convAcc + (size_t)z * 28672;
#pragma unroll 4
    for (int i2 = 0; i2 < 28; ++i2) *(f32x4*)(za + (size_t)(i2 * 256 + tid) * 4) = zz;
    if (tid < 56) *(f32x4*)(att + (size_t)(z * 56 + tid) * 4) = zz;
    if (tid < 64) *(f32x4*)(relations + (size_t)(z * 64 + tid) * 4) = zz;
  } else {
    int z = b - 384;
    for (int e = tid; e < 576; e += 256) {
      int idx = z * 576 + e;
      int nn = idx / 288, kk = idx - nn * 288;
      hp_w0t[idx] = (kk < 258) ? f2b(hp_w0[kk * 256 + nn]) : (u16)0;
    }
    for (int e = tid; e < 576; e += 256) {
      int idx = z * 576 + e;
      int nn = idx / 288, kk = idx - nn * 288;
      gt_w0t[idx] = (kk < 258) ? f2b(gt_w0[kk * 256 + nn]) : (u16)0;
    }
    for (int e = tid; e < 512; e += 256) {
      int idx = z * 512 + e;
      int nn = idx >> 8, kk = idx & 255;
      gt_w1t[idx] = f2b(gt_w1[kk * 256 + nn]);
    }
  }
  gbar(bar, 0);

  // ---- S1: conv (split-K 2, 512 blocks = 2/CU) ----
  conv_core(smem, b, imgT, W2, convAcc);
  gbar(bar, 1);

  // ---- S2: convAcc + bias -> qeb bf16 cols 0..127 ----
  for (int u2 = b * 256 + tid; u2 < 128 * 196 * 32; u2 += NBLK * 256) {
    int row196 = u2 >> 5;
    int c0 = (u2 & 31) << 2;
    int n = row196 / 196, o = row196 - n * 196;
    size_t row = (size_t)(n * 224 + o);
    float4 v = *(const float4*)(convAcc + (row << 7) + c0);
    float4 bb = *(const float4*)(conv_b + c0);
    ushort4 pk;
    pk.x = f2b(v.x + bb.x); pk.y = f2b(v.y + bb.y);
    pk.z = f2b(v.z + bb.z); pk.w = f2b(v.w + bb.w);
    *(ushort4*)(qeb + row * 288 + c0) = pk;
  }
  gbar(bar, 2);

  // ---- S3: h_psi -> att ----
  gemm_core<0>(smem, b & 255, b >> 8, qeb, hp_w0t, 288, 9, hp_b0, hp_w1, att, nullptr);
  gbar(bar, 3);

  // ---- S4: softmax select -> bias2 ----
  if (b < 128) sel_part(smem, b, att, qeb, gt_w0, gt_b0, bias2);
  gbar(bar, 4);

  // ---- S5: g_theta L1 -> g1 (aliases convAcc) ----
  gemm_core<1>(smem, b & 255, b >> 8, qeb, gt_w0t, 288, 9, bias2, nullptr, nullptr, (u16*)convAcc);
  gbar(bar, 5);

  // ---- S6: g_theta L2 -> relations ----
  gemm_core<2>(smem, b & 255, b >> 8, (const u16*)convAcc, gt_w1t, 256, 8, gt_b1, nullptr,
               relations, nullptr);
  gbar(bar, 6);

  // ---- S7: f_phi -> out ----
  if (b < 128) fphi_part(smem, b, relations, fp_w0, fp_b0, fp_w1, fp_b1, out);
}

extern "C" void kernel_launch(void* const* d_in, const int* in_sizes, int n_in,
                              void* d_out, int out_size, void* d_ws, size_t ws_size,
                              hipStream_t stream) {
  const float* image = (const float*)d_in[0];
  const float* code = (const float*)d_in[1];
  const float* conv_w = (const float*)d_in[2];
  const float* conv_b = (const float*)d_in[3];
  const float* hp_w0 = (const float*)d_in[4];
  const float* hp_b0 = (const float*)d_in[5];
  const float* hp_w1 = (const float*)d_in[6];
  /* hp_b1: softmax shift-invariant, dropped */
  const float* gt_w0 = (const float*)d_in[8];
  const float* gt_b0 = (const float*)d_in[9];
  const float* gt_w1 = (const float*)d_in[10];
  const float* gt_b1 = (const float*)d_in[11];
  const float* fp_w0 = (const float*)d_in[12];
  const float* fp_b0 = (const float*)d_in[13];
  const float* fp_w1 = (const float*)d_in[14];
  const float* fp_b1 = (const float*)d_in[15];
  float* out = (float*)d_out;

  char* p = (char*)d_ws;
  u16* imgT = (u16*)p;   p += (size_t)128 * 256 * 1024 * 2;   // 67.1 MB
  u16* W2 = (u16*)p;     p += (size_t)9 * 128 * 1024 * 2;     // 2.36 MB
  u16* qeb = (u16*)p;    p += (size_t)ROWS * 288 * 2;         // 16.5 MB
  u16* hp_w0t = (u16*)p; p += (size_t)256 * 288 * 2;
  u16* gt_w0t = (u16*)p; p += (size_t)256 * 288 * 2;
  u16* gt_w1t = (u16*)p; p += (size_t)256 * 256 * 2;
  float* att = (float*)p;   p += (size_t)ROWS * 4;
  float* bias2 = (float*)p; p += (size_t)128 * 256 * 4;
  float* convAcc = (float*)p; p += (size_t)ROWS * 128 * 4;    // 14.7 MB; reused as g1
  float* relations = (float*)p; p += (size_t)128 * 256 * 4;
  int* bar = (int*)p;    p += 64;

  init_bar<<<1, 64, 0, stream>>>(bar);
  mega<<<NBLK, 256, 0, stream>>>(image, code, conv_w, conv_b, hp_w0, hp_b0, hp_w1,
                                 gt_w0, gt_b0, gt_w1, gt_b1, fp_w0, fp_b0, fp_w1, fp_b1,
                                 imgT, W2, qeb, hp_w0t, gt_w0t, gt_w1t,
                                 att, bias2, convAcc, relations, out, bar);
}

// Round 7
// 534.430 us; speedup vs baseline: 2.2407x; 1.8930x over previous
//
#include <hip/hip_runtime.h>
#include <stdint.h>

typedef unsigned short u16;
typedef __bf16 bf16x8 __attribute__((ext_vector_type(8)));
typedef float f32x4 __attribute__((ext_vector_type(4)));
typedef unsigned short u16x8 __attribute__((ext_vector_type(8)));

#define NBLK 512
#define ROWS (128 * 224)

// ---------- helpers ----------
__device__ __forceinline__ u16 f2b(float f) {
  union { float f; uint32_t u; } v; v.f = f;
  uint32_t r = v.u + 0x7fffu + ((v.u >> 16) & 1u);
  return (u16)(r >> 16);
}
__device__ __forceinline__ float b2f(u16 b) {
  union { float f; uint32_t u; } v; v.u = ((uint32_t)b) << 16;
  return v.f;
}
__device__ __forceinline__ void g2l16(const void* g, void* l) {
  __builtin_amdgcn_global_load_lds(
      (const __attribute__((address_space(1))) void*)g,
      (__attribute__((address_space(3))) void*)l, 16, 0, 0);
}

// ---------- per-n flag sync (NO cache-wide invalidates anywhere) ----------
// arrive: syncthreads drains all waves' vmcnt (stores are in L2); release fence
// emits buffer_wbl2 (writeback ONLY - lines stay valid) so data is at MALL even
// if consumer is another XCD; then flag-add at the coherence point.
// wait: uncached poll; consumer reads are first-touch, so no acquire-inv needed.
__device__ __forceinline__ void arrive(int* flag) {
  __syncthreads();
  if (threadIdx.x == 0) {
    __builtin_amdgcn_fence(__ATOMIC_RELEASE, "agent");
    atomicAdd(flag, 1);
  }
}
__device__ __forceinline__ void wait_cnt(int* flag, int target) {
  if (threadIdx.x == 0) {
    int t = 0;
    while (__hip_atomic_load(flag, __ATOMIC_RELAXED, __HIP_MEMORY_SCOPE_SYSTEM) < target) {
      __builtin_amdgcn_s_sleep(4);
      if (++t > (1 << 19)) break;  // escape hatch: wrong answer instead of hang
    }
  }
  __syncthreads();
}

// ---------- node 1: weight repacks + zero-init ----------
__global__ __launch_bounds__(256) void prep(
    const float* __restrict__ conv_w, const float* __restrict__ hp_w0,
    const float* __restrict__ gt_w0, const float* __restrict__ gt_w1,
    u16* __restrict__ W2, u16* __restrict__ hp_w0t,
    u16* __restrict__ gt_w0t, u16* __restrict__ gt_w1t,
    float* __restrict__ convAcc, float* __restrict__ att,
    float* __restrict__ relations, int* __restrict__ flags) {
  __shared__ float wb[9216];
  int b = blockIdx.x, tid = threadIdx.x;
  if (b < 128) {                           // W2: [cf][cin][9] -> [9][cf][cin] bf16
    for (int e = tid; e < 9216; e += 256) wb[e] = conv_w[(size_t)b * 9216 + e];
    __syncthreads();
    int cin = tid * 4;
#pragma unroll
    for (int s = 0; s < 9; ++s) {
      ushort4 v;
      v.x = f2b(wb[(cin + 0) * 9 + s]);
      v.y = f2b(wb[(cin + 1) * 9 + s]);
      v.z = f2b(wb[(cin + 2) * 9 + s]);
      v.w = f2b(wb[(cin + 3) * 9 + s]);
      *(ushort4*)(W2 + (size_t)s * 131072 + b * 1024 + cin) = v;
    }
    return;
  }
  b -= 128;
  if (b < 288) {                           // hp_w0t[256][288], K zero-padded
    int idx = b * 256 + tid;
    int nn = idx / 288, kk = idx - nn * 288;
    hp_w0t[idx] = (kk < 258) ? f2b(hp_w0[kk * 256 + nn]) : (u16)0;
    return;
  }
  b -= 288;
  if (b < 288) {                           // gt_w0t[256][288]
    int idx = b * 256 + tid;
    int nn = idx / 288, kk = idx - nn * 288;
    gt_w0t[idx] = (kk < 258) ? f2b(gt_w0[kk * 256 + nn]) : (u16)0;
    return;
  }
  b -= 288;
  if (b < 256) {                           // gt_w1t[256][256]
    int idx = b * 256 + tid;
    int nn = idx >> 8, kk = idx & 255;
    gt_w1t[idx] = f2b(gt_w1[kk * 256 + nn]);
    return;
  }
  b -= 256;
  if (b < 896) {                           // zero convAcc (ROWS*128 f32)
    float4 z = {0.f, 0.f, 0.f, 0.f};
#pragma unroll
    for (int k = 0; k < 4; ++k) ((float4*)convAcc)[b * 1024 + k * 256 + tid] = z;
    return;
  }
  b -= 896;
  if (b < 28) {                            // zero att (ROWS f32)
    float4 z = {0.f, 0.f, 0.f, 0.f};
    ((float4*)att)[b * 256 + tid] = z;
    return;
  }
  b -= 28;
  if (b < 32) {                            // zero relations (128*256 f32)
    float4 z = {0.f, 0.f, 0.f, 0.f};
    ((float4*)relations)[b * 256 + tid] = z;
    return;
  }
  b -= 32;
  if (b == 0) {                            // zero flags (128*8)
#pragma unroll
    for (int k = 0; k < 4; ++k) flags[k * 256 + tid] = 0;
  }
}

// ---------- conv implicit GEMM core (R6-proven body), split-K 2 ----------
__device__ void conv_core(char* smem, int n, int oh, int ks,
                          const u16* __restrict__ imgT, const u16* __restrict__ W2,
                          float* __restrict__ convAcc) {
  u16* lA = (u16*)smem;                    // 112*64*2 = 14,336
  u16* lB = (u16*)(smem + 14336);          // 128*64*2 = 16,384
  int tid = threadIdx.x, lane = tid & 63, w = tid >> 6;
  int oBase = oh * 112;
  size_t nBase = (size_t)n << 8;
  int rowIn = lane >> 3;
  int cA = ((lane & 7) ^ rowIn) << 3;

  int yxA[4];
#pragma unroll
  for (int ii = 0; ii < 4; ++ii) {
    int t2 = w + ii * 4;
    int o = oBase + t2 * 8 + rowIn;
    bool valid = o < 196;
    int y = o / 14, x = o - y * 14;
    yxA[ii] = valid ? (y * 16 + x) : 0;
  }

  f32x4 acc[7][2];
#pragma unroll
  for (int mt = 0; mt < 7; ++mt)
#pragma unroll
    for (int j = 0; j < 2; ++j) acc[mt][j] = (f32x4){0.f, 0.f, 0.f, 0.f};

  int l = lane & 15, q = lane >> 4;
  int kbase = ks << 9;
  for (int u = 0; u < 72; ++u) {
    int s = u >> 3;
    int k0 = kbase + ((u & 7) << 6);
    int s3 = s / 3;
    int off = s3 * 16 + (s - s3 * 3);
    const u16* Ws = W2 + ((size_t)(s * 128) << 10);
    __syncthreads();
    g2l16(imgT + ((nBase + (size_t)(yxA[0] + off)) << 10) + k0 + cA, &lA[(w) * 512]);
    g2l16(imgT + ((nBase + (size_t)(yxA[1] + off)) << 10) + k0 + cA, &lA[(w + 4) * 512]);
    g2l16(imgT + ((nBase + (size_t)(yxA[2] + off)) << 10) + k0 + cA, &lA[(w + 8) * 512]);
    if (w < 2)
      g2l16(imgT + ((nBase + (size_t)(yxA[3] + off)) << 10) + k0 + cA, &lA[(w + 12) * 512]);
#pragma unroll
    for (int ii = 0; ii < 4; ++ii) {
      int t2 = w + ii * 4;
      g2l16(Ws + ((size_t)(t2 * 8 + rowIn) << 10) + k0 + cA, &lB[t2 * 512]);
    }
    __syncthreads();
#pragma unroll
    for (int kk = 0; kk < 2; ++kk) {
      int co = ((((kk << 2) | q) ^ (l & 7)) << 3);
      bf16x8 af[7];
#pragma unroll
      for (int mt = 0; mt < 7; ++mt)
        af[mt] = *(const bf16x8*)&lA[(mt * 16 + l) * 64 + co];
#pragma unroll
      for (int jj = 0; jj < 2; ++jj) {
        bf16x8 bb = *(const bf16x8*)&lB[(w * 32 + jj * 16 + l) * 64 + co];
#pragma unroll
        for (int mt = 0; mt < 7; ++mt)
          acc[mt][jj] = __builtin_amdgcn_mfma_f32_16x16x32_bf16(af[mt], bb, acc[mt][jj], 0, 0, 0);
      }
    }
  }
#pragma unroll
  for (int mt = 0; mt < 7; ++mt) {
    int o = oBase + mt * 16 + q * 4;
#pragma unroll
    for (int r4 = 0; r4 < 4; ++r4) {
      if (o + r4 < 196) {
        float* dst = convAcc + (size_t)(n * 224 + o + r4) * 128 + w * 32 + l;
        atomicAdd(dst, acc[mt][0][r4]);
        atomicAdd(dst + 16, acc[mt][1][r4]);
      }
    }
  }
}

// ---------- shared 112x128 GEMM accumulate (R6 staging pattern) ----------
__device__ void gemm_acc(char* smem, const u16* __restrict__ A, const u16* __restrict__ Bt,
                         int cBase, int KP, int KC, f32x4 acc[7][2]) {
  u16* lA = (u16*)smem;                    // 7,168
  u16* lB = (u16*)(smem + 7168);           // 8,192
  int tid = threadIdx.x, lane = tid & 63, w = tid >> 6;
  int kb = (((lane & 3) ^ ((lane >> 3) & 3)) << 3);
  const u16* gA0 = A + (size_t)(w * 16 + (lane >> 2)) * KP + kb;
  const u16* gA1 = A + (size_t)((w + 4) * 16 + (lane >> 2)) * KP + kb;
  bool has1 = (w < 3);
  const u16* gB0 = Bt + (size_t)(cBase + w * 16 + (lane >> 2)) * KP + kb;
  const u16* gB1 = Bt + (size_t)(cBase + (w + 4) * 16 + (lane >> 2)) * KP + kb;
  int l = lane & 15, q = lane >> 4;
  int co = ((q ^ ((l >> 1) & 3)) << 3);
  int colW = w * 32;
  for (int cb = 0; cb < KC; ++cb) {
    __syncthreads();
    g2l16(gA0 + cb * 32, &lA[w * 512]);
    if (has1) g2l16(gA1 + cb * 32, &lA[(w + 4) * 512]);
    g2l16(gB0 + cb * 32, &lB[w * 512]);
    g2l16(gB1 + cb * 32, &lB[(w + 4) * 512]);
    __syncthreads();
    bf16x8 af[7];
#pragma unroll
    for (int mt = 0; mt < 7; ++mt)
      af[mt] = *(const bf16x8*)&lA[(mt * 16 + l) * 32 + co];
#pragma unroll
    for (int j = 0; j < 2; ++j) {
      bf16x8 bfr = *(const bf16x8*)&lB[(colW + j * 16 + l) * 32 + co];
#pragma unroll
      for (int mt = 0; mt < 7; ++mt)
        acc[mt][j] = __builtin_amdgcn_mfma_f32_16x16x32_bf16(af[mt], bfr, acc[mt][j], 0, 0, 0);
    }
  }
}

// ---------- softmax select -> per-n bias2 (R6 body) ----------
__device__ void sel_part(char* smem, int n, const float* __restrict__ att,
                         const u16* __restrict__ qeb, const float* __restrict__ gt_w0,
                         const float* __restrict__ gt_b0, float* __restrict__ bias2) {
  float* sm = (float*)smem;
  float* red = sm + 200;
  float* part = red + 8;
  float* sel = part + 520;
  int t = threadIdx.x, w = t >> 6, lane = t & 63;
  float a = (t < 196) ? att[n * 224 + t] : -1e30f;
  float m = a;
  for (int mask = 1; mask < 64; mask <<= 1) m = fmaxf(m, __shfl_xor(m, mask, 64));
  if (lane == 0) red[w] = m;
  __syncthreads();
  float M = fmaxf(fmaxf(red[0], red[1]), fmaxf(red[2], red[3]));
  float e = (t < 196) ? expf(a - M) : 0.f;
  float sAcc = e;
  for (int mask = 1; mask < 64; mask <<= 1) sAcc += __shfl_xor(sAcc, mask, 64);
  if (lane == 0) red[4 + w] = sAcc;
  __syncthreads();
  float S = red[4] + red[5] + red[6] + red[7];
  if (t < 196) sm[t] = e / S;
  __syncthreads();
  float p1 = 0.f, p2 = 0.f, p3 = 0.f;
  for (int o = w; o < 196; o += 4) {
    float s = sm[o];
    const u16* row = qeb + (size_t)(n * 224 + o) * 288;
    p1 += s * b2f(row[lane]);
    p2 += s * b2f(row[64 + lane]);
    if (lane < 2) p3 += s * b2f(row[128 + lane]);
  }
  part[w * 130 + lane] = p1;
  part[w * 130 + 64 + lane] = p2;
  if (lane < 2) part[w * 130 + 128 + lane] = p3;
  __syncthreads();
  if (t < 130) sel[t] = part[t] + part[130 + t] + part[260 + t] + part[390 + t];
  __syncthreads();
  float acc2 = gt_b0[t];
  for (int d = 0; d < 130; ++d) acc2 += sel[d] * gt_w0[(258 + d) * 256 + t];
  bias2[n * 256 + t] = acc2;
}

// ---------- f_phi (R6 body) ----------
__device__ void fphi_part(char* smem, int n, const float* __restrict__ relations,
                          const float* __restrict__ fp_w0, const float* __restrict__ fp_b0,
                          const float* __restrict__ fp_w1, const float* __restrict__ fp_b1,
                          float* __restrict__ out) {
  float* rel = (float*)smem;
  float* f = rel + 256;
  int t = threadIdx.x;
  rel[t] = relations[n * 256 + t];
  __syncthreads();
  float acc = fp_b0[t];
  for (int k = 0; k < 256; ++k) acc += rel[k] * fp_w0[k * 256 + t];
  f[t] = fmaxf(acc, 0.f);
  __syncthreads();
  if (t < 32) {
    float o = fp_b1[0];
    for (int k = 0; k < 256; ++k) o += f[k] * fp_w1[k * 32 + t];
    out[n * 32 + t] = o;
  }
}

// ---------- node 2: per-n pipelined main kernel ----------
__global__ __launch_bounds__(256, 2) void main_k(
    const float* image, const float* code, const float* conv_b,
    const float* hp_b0, const float* hp_w1,
    const float* gt_w0, const float* gt_b0, const float* gt_b1,
    const float* fp_w0, const float* fp_b0, const float* fp_w1, const float* fp_b1,
    u16* imgT, u16* W2, u16* qeb, u16* hp_w0t, u16* gt_w0t, u16* gt_w1t,
    float* att, float* bias2, float* convAcc, float* relations, float* out,
    int* flags) {
  __shared__ __align__(16) char smem[30720];
  int b = blockIdx.x, tid = threadIdx.x;
  int xcd = b & 7, i = b >> 3;             // b%8 = XCD (locality heuristic only;
  int nl = i >> 2, quad = i & 3;           //  correctness holds via wbl2 release)
  int n = xcd * 16 + nl;
  int oh = quad >> 1, ks = quad & 1;
  int* fl = flags + n * 8;
  int lane = tid & 63, w = tid >> 6, l = lane & 15, q4 = lane >> 4;
  u16* g1 = (u16*)convAcc;                 // alias: convAcc dead after T2

  // ---- T0: image(n) -> imgT(n) transpose (4 blocks split 256 spatials) ----
  {
    float (*t)[56] = (float(*)[56])smem;   // 64 cin x 56 sp fp32 = 14,336 B
    int s0 = quad * 56 - 14;               // spi window for this spg strip
    for (int c0 = 0; c0 < 1024; c0 += 64) {
      const float* src = image + ((size_t)n * 1024 + c0) * 196;
      __syncthreads();
      for (int e = tid; e < 64 * 56; e += 256) {
        int cin = e / 56, r = e - cin * 56;
        int spi = s0 + r;
        t[cin][r] = (spi >= 0 && spi < 196) ? src[cin * 196 + spi] : 0.f;
      }
      __syncthreads();
      int cg = tid & 7, sg = tid >> 3;
      for (int it = 0; it < 2; ++it) {
        int spg = quad * 64 + it * 32 + sg;
        int gy = spg >> 4, gx = spg & 15;
        bool valid = (gy >= 1 && gy <= 14 && gx >= 1 && gx <= 14);
        int idx = (gy - 1) * 14 + (gx - 1) - s0;
        u16x8 v;
#pragma unroll
        for (int j = 0; j < 8; ++j) v[j] = valid ? f2b(t[cg * 8 + j][idx]) : (u16)0;
        *(u16x8*)(imgT + (((size_t)(n * 256 + spg)) << 10) + c0 + cg * 8) = v;
      }
    }
  }
  arrive(fl + 0);
  wait_cnt(fl + 0, 4);

  // ---- T1: conv (quad = oh x ks split-K), atomics into convAcc(n) ----
  conv_core(smem, n, oh, ks, imgT, W2, convAcc);
  arrive(fl + 1);
  wait_cnt(fl + 1, 4);

  // ---- T2: convAcc+bias -> qeb cols 0..127; template fill cols 128..287 ----
  {
    u16* tmpl = (u16*)smem;
    if (tid < 160) {
      int c = 128 + tid;
      u16 v = 0;
      if (c >= 130 && c < 258) v = f2b(code[n * 128 + c - 130]);
      tmpl[tid] = v;
    }
    __syncthreads();
    for (int idx = tid; idx < 49 * 32; idx += 256) {
      int o = quad * 49 + (idx >> 5);
      int c4 = (idx & 31) << 2;
      size_t row = (size_t)(n * 224 + o);
      float4 v = *(const float4*)(convAcc + (row << 7) + c4);
      float4 bb = *(const float4*)(conv_b + c4);
      ushort4 pk;
      pk.x = f2b(v.x + bb.x); pk.y = f2b(v.y + bb.y);
      pk.z = f2b(v.z + bb.z); pk.w = f2b(v.w + bb.w);
      *(ushort4*)(qeb + row * 288 + c4) = pk;
    }
    for (int idx = tid; idx < 49 * 20; idx += 256) {
      int o = quad * 49 + idx / 20, j = idx - (idx / 20) * 20;
      u16x8 v = *(const u16x8*)&tmpl[j * 8];
      if (j == 0) {
        int y = o / 14, x = o - y * 14;
        v[0] = f2b(-1.f + 2.f * y / 13.f);
        v[1] = f2b(-1.f + 2.f * x / 13.f);
      }
      *(u16x8*)(qeb + (size_t)(n * 224 + o) * 288 + 128 + j * 8) = v;
    }
  }
  arrive(fl + 2);

  size_t rowBase = (size_t)(n * 224 + oh * 112);

  // ---- T3: h_psi -> att (only ks==0 blocks; both 128-col halves) ----
  if (ks == 0) {
    wait_cnt(fl + 2, 4);
    float attp[7][4];
#pragma unroll
    for (int mt = 0; mt < 7; ++mt)
#pragma unroll
      for (int r = 0; r < 4; ++r) attp[mt][r] = 0.f;
    for (int by = 0; by < 2; ++by) {
      f32x4 acc[7][2];
#pragma unroll
      for (int mt = 0; mt < 7; ++mt)
#pragma unroll
        for (int j = 0; j < 2; ++j) acc[mt][j] = (f32x4){0.f, 0.f, 0.f, 0.f};
      gemm_acc(smem, qeb + rowBase * 288, hp_w0t, by * 128, 288, 9, acc);
#pragma unroll
      for (int j = 0; j < 2; ++j) {
        int col = by * 128 + w * 32 + j * 16 + l;
        float b0 = hp_b0[col], w1 = hp_w1[col];
#pragma unroll
        for (int mt = 0; mt < 7; ++mt)
#pragma unroll
          for (int r = 0; r < 4; ++r) {
            float v = fmaxf(acc[mt][j][r] + b0, 0.f);
            attp[mt][r] += v * w1;
          }
      }
    }
#pragma unroll
    for (int mt = 0; mt < 7; ++mt)
#pragma unroll
      for (int r = 0; r < 4; ++r) {
        float p = attp[mt][r];
        p += __shfl_xor(p, 1, 64);
        p += __shfl_xor(p, 2, 64);
        p += __shfl_xor(p, 4, 64);
        p += __shfl_xor(p, 8, 64);
        if (l == 0) atomicAdd(&att[rowBase + mt * 16 + q4 * 4 + r], p);
      }
  }
  arrive(fl + 3);                          // ks==1 blocks arrive right after T2

  // ---- T4: softmax select -> bias2(n) (quad0 only) ----
  if (quad == 0) {
    wait_cnt(fl + 3, 4);
    sel_part(smem, n, att, qeb, gt_w0, gt_b0, bias2);
  }
  arrive(fl + 4);
  wait_cnt(fl + 4, 4);

  // ---- T5: g_theta L1 -> g1 (quad = oh x nc) ----
  {
    f32x4 acc[7][2];
#pragma unroll
    for (int mt = 0; mt < 7; ++mt)
#pragma unroll
      for (int j = 0; j < 2; ++j) acc[mt][j] = (f32x4){0.f, 0.f, 0.f, 0.f};
    gemm_acc(smem, qeb + rowBase * 288, gt_w0t, ks * 128, 288, 9, acc);
#pragma unroll
    for (int mt = 0; mt < 7; ++mt)
#pragma unroll
      for (int j = 0; j < 2; ++j) {
        int col = ks * 128 + w * 32 + j * 16 + l;
        float bb = bias2[n * 256 + col];
#pragma unroll
        for (int r = 0; r < 4; ++r) {
          size_t row = rowBase + mt * 16 + q4 * 4 + r;
          g1[row * 256 + col] = f2b(fmaxf(acc[mt][j][r] + bb, 0.f));
        }
      }
  }
  arrive(fl + 5);
  wait_cnt(fl + 5, 4);

  // ---- T6: g_theta L2 + masked row-sum -> relations(n) ----
  {
    f32x4 acc[7][2];
#pragma unroll
    for (int mt = 0; mt < 7; ++mt)
#pragma unroll
      for (int j = 0; j < 2; ++j) acc[mt][j] = (f32x4){0.f, 0.f, 0.f, 0.f};
    gemm_acc(smem, g1 + rowBase * 256, gt_w1t, ks * 128, 256, 8, acc);
#pragma unroll
    for (int j = 0; j < 2; ++j) {
      int col = ks * 128 + w * 32 + j * 16 + l;
      float bb = gt_b1[col];
      float sum = 0.f;
#pragma unroll
      for (int mt = 0; mt < 7; ++mt)
#pragma unroll
        for (int r = 0; r < 4; ++r) {
          int o = oh * 112 + mt * 16 + q4 * 4 + r;
          if (o < 196) sum += fmaxf(acc[mt][j][r] + bb, 0.f);
        }
      sum += __shfl_xor(sum, 16, 64);
      sum += __shfl_xor(sum, 32, 64);
      if (q4 == 0) atomicAdd(&relations[n * 256 + col], sum);
    }
  }
  arrive(fl + 6);

  // ---- T7: f_phi -> out (quad0 only) ----
  if (quad == 0) {
    wait_cnt(fl + 6, 4);
    fphi_part(smem, n, relations, fp_w0, fp_b0, fp_w1, fp_b1, out);
  }
}

extern "C" void kernel_launch(void* const* d_in, const int* in_sizes, int n_in,
                              void* d_out, int out_size, void* d_ws, size_t ws_size,
                              hipStream_t stream) {
  const float* image = (const float*)d_in[0];
  const float* code = (const float*)d_in[1];
  const float* conv_w = (const float*)d_in[2];
  const float* conv_b = (const float*)d_in[3];
  const float* hp_w0 = (const float*)d_in[4];
  const float* hp_b0 = (const float*)d_in[5];
  const float* hp_w1 = (const float*)d_in[6];
  /* hp_b1: softmax shift-invariant, dropped */
  const float* gt_w0 = (const float*)d_in[8];
  const float* gt_b0 = (const float*)d_in[9];
  const float* gt_w1 = (const float*)d_in[10];
  const float* gt_b1 = (const float*)d_in[11];
  const float* fp_w0 = (const float*)d_in[12];
  const float* fp_b0 = (const float*)d_in[13];
  const float* fp_w1 = (const float*)d_in[14];
  const float* fp_b1 = (const float*)d_in[15];
  float* out = (float*)d_out;

  char* p = (char*)d_ws;
  u16* imgT = (u16*)p;   p += (size_t)128 * 256 * 1024 * 2;   // 67.1 MB
  u16* W2 = (u16*)p;     p += (size_t)9 * 128 * 1024 * 2;     // 2.36 MB
  u16* qeb = (u16*)p;    p += (size_t)ROWS * 288 * 2;         // 16.5 MB
  u16* hp_w0t = (u16*)p; p += (size_t)256 * 288 * 2;
  u16* gt_w0t = (u16*)p; p += (size_t)256 * 288 * 2;
  u16* gt_w1t = (u16*)p; p += (size_t)256 * 256 * 2;
  float* att = (float*)p;   p += (size_t)ROWS * 4;
  float* bias2 = (float*)p; p += (size_t)128 * 256 * 4;
  float* convAcc = (float*)p; p += (size_t)ROWS * 128 * 4;    // 14.7 MB; aliased as g1
  float* relations = (float*)p; p += (size_t)128 * 256 * 4;
  int* flags = (int*)p;  p += 128 * 8 * 4;

  prep<<<1917, 256, 0, stream>>>(conv_w, hp_w0, gt_w0, gt_w1,
                                 W2, hp_w0t, gt_w0t, gt_w1t,
                                 convAcc, att, relations, flags);
  main_k<<<NBLK, 256, 0, stream>>>(image, code, conv_b, hp_b0, hp_w1,
                                   gt_w0, gt_b0, gt_b1, fp_w0, fp_b0, fp_w1, fp_b1,
                                   imgT, W2, qeb, hp_w0t, gt_w0t, gt_w1t,
                                   att, bias2, convAcc, relations, out, flags);
}